// Round 3
// baseline (340.121 us; speedup 1.0000x reference)
//
#include <hip/hip_runtime.h>
#include <math.h>

#define N_SRC  2048
#define N_GRID 50000
#define N_LOCS 500
#define K_TOP  5
#define SPB    8                    // sources per block (topk)
#define NCHUNK 16                   // grid chunks
#define CHUNK  (N_GRID / NCHUNK)    // 3125
#define CAP    128                  // LDS candidate list capacity per source
#define NPART  (NCHUNK * K_TOP)     // 80 partial keys per source

typedef unsigned long long u64;

// Monotone pack: order-preserving f32 bits <<32 | grid index.
// Smallest key == smallest d2; ties -> smallest index (matches jax.lax.top_k).
__device__ __forceinline__ u64 pack_key(float d2, int j) {
    unsigned int b = __float_as_uint(d2);
    unsigned int m = (unsigned int)(-(int)(b >> 31)) | 0x80000000u;
    b ^= m;
    return ((u64)b << 32) | (u64)(unsigned int)j;
}

// Identical fmaf sequence in both passes -> bit-identical d2.
__device__ __forceinline__ float dist2(float sx, float sy, float sz, float s2,
                                       float4 g) {
    float dot = fmaf(sz, g.z, fmaf(sy, g.y, sx * g.x));
    return fmaf(-2.0f, dot, s2 + g.w);
}

// Insert x into sorted-ascending {a0..a4}; caller gates on x < a4.
__device__ __forceinline__ void vins5(float& a0, float& a1, float& a2,
                                      float& a3, float& a4, float x) {
    bool c3 = x < a3, c2 = x < a2, c1 = x < a1, c0 = x < a0;
    a4 = c3 ? a3 : x;
    a3 = c2 ? a2 : (c3 ? x : a3);
    a2 = c1 ? a1 : (c2 ? x : a2);
    a1 = c0 ? a0 : (c1 ? x : a1);
    a0 = c0 ? x  : a0;
}

__device__ __forceinline__ void kins5(u64& a0, u64& a1, u64& a2,
                                      u64& a3, u64& a4, u64 x) {
    if (x >= a4) return;
    bool c3 = x < a3, c2 = x < a2, c1 = x < a1, c0 = x < a0;
    a4 = c3 ? a3 : x;
    a3 = c2 ? a2 : (c3 ? x : a3);
    a2 = c1 ? a1 : (c2 ? x : a2);
    a1 = c0 ? a0 : (c1 ? x : a1);
    a0 = c0 ? x  : a0;
}

// grid -> (x,y,z)/1000 + precomputed g2, as float4
__global__ __launch_bounds__(256) void prep_kernel(
    const float* __restrict__ grid, float4* __restrict__ g4)
{
    int j = blockIdx.x * 256 + threadIdx.x;
    if (j < N_GRID) {
        float gx = grid[(size_t)j*3 + 0] / 1000.0f;
        float gy = grid[(size_t)j*3 + 1] / 1000.0f;
        float gz = grid[(size_t)j*3 + 2] / 1000.0f;
        float g2 = fmaf(gz, gz, fmaf(gy, gy, gx * gx));
        g4[j] = make_float4(gx, gy, gz, g2);
    }
}

__global__ __launch_bounds__(256) void topk_kernel(
    const float* __restrict__ src, const float4* __restrict__ g4,
    u64* __restrict__ part)
{
    __shared__ float minsL[SPB][256];
    __shared__ float TL[SPB];
    __shared__ int   cntL[SPB];
    __shared__ u64   listL[SPB][CAP];

    const int tid   = threadIdx.x;
    const int grp   = blockIdx.x & 255;        // source octet
    const int chunk = blockIdx.x >> 8;         // grid chunk
    const int b0    = grp * SPB;
    const int j0    = chunk * CHUNK;
    const int j1    = j0 + CHUNK;

    float sx[SPB], sy[SPB], sz[SPB], s2[SPB];
    #pragma unroll
    for (int s = 0; s < SPB; ++s) {
        const float* p = src + (size_t)(b0 + s) * 3;
        float x = p[0] / 1000.0f, y = p[1] / 1000.0f, z = p[2] / 1000.0f;
        sx[s] = x; sy[s] = y; sz[s] = z;
        s2[s] = fmaf(z, z, fmaf(y, y, x * x));
    }

    // ---- pass A: per-thread min distance per source ----
    float mn[SPB];
    #pragma unroll
    for (int s = 0; s < SPB; ++s) mn[s] = INFINITY;

    for (int j = j0 + tid; j < j1; j += 256) {
        float4 g = g4[j];
        #pragma unroll
        for (int s = 0; s < SPB; ++s)
            mn[s] = fminf(mn[s], dist2(sx[s], sy[s], sz[s], s2[s], g));
    }
    #pragma unroll
    for (int s = 0; s < SPB; ++s) minsL[s][tid] = mn[s];
    if (tid < SPB) cntL[tid] = 0;
    __syncthreads();

    // ---- threshold T[s] = 5th smallest of 256 per-thread minima ----
    // (>= true 5th smallest distance: the 5 smallest minima belong to 5
    //  distinct grid points, so the true top-5 all satisfy d2 <= T)
    const int lane = tid & 63;
    const int w    = tid >> 6;
    for (int s = w; s < SPB; s += 4) {
        float a0 = INFINITY, a1 = INFINITY, a2 = INFINITY,
              a3 = INFINITY, a4 = INFINITY;
        #pragma unroll
        for (int q = 0; q < 4; ++q) {
            float x = minsL[s][lane * 4 + q];
            if (x < a4) vins5(a0, a1, a2, a3, a4, x);
        }
        #pragma unroll
        for (int off = 32; off >= 1; off >>= 1) {
            float b0_ = __shfl_down(a0, off), b1_ = __shfl_down(a1, off),
                  b2_ = __shfl_down(a2, off), b3_ = __shfl_down(a3, off),
                  b4_ = __shfl_down(a4, off);
            if (b0_ < a4) vins5(a0, a1, a2, a3, a4, b0_);
            if (b1_ < a4) vins5(a0, a1, a2, a3, a4, b1_);
            if (b2_ < a4) vins5(a0, a1, a2, a3, a4, b2_);
            if (b3_ < a4) vins5(a0, a1, a2, a3, a4, b3_);
            if (b4_ < a4) vins5(a0, a1, a2, a3, a4, b4_);
        }
        if (lane == 0) TL[s] = a4;
    }
    __syncthreads();

    float Ts[SPB];
    #pragma unroll
    for (int s = 0; s < SPB; ++s) Ts[s] = TL[s];

    // ---- pass B: collect candidates with d2 <= T (expected ~5-10) ----
    for (int j = j0 + tid; j < j1; j += 256) {
        float4 g = g4[j];
        #pragma unroll
        for (int s = 0; s < SPB; ++s) {
            float d2 = dist2(sx[s], sy[s], sz[s], s2[s], g);
            if (d2 <= Ts[s]) {
                int p = atomicAdd(&cntL[s], 1);
                if (p < CAP) listL[s][p] = pack_key(d2, j);
            }
        }
    }
    __syncthreads();

    // ---- exact top-5 of the collected list (packed u64: exact ties) ----
    for (int s = w; s < SPB; s += 4) {
        int n = cntL[s]; n = n < CAP ? n : CAP;
        u64 a0 = ~0ull, a1 = ~0ull, a2 = ~0ull, a3 = ~0ull, a4 = ~0ull;
        u64 x0 = (lane      < n) ? listL[s][lane]      : ~0ull;
        u64 x1 = (lane + 64 < n) ? listL[s][lane + 64] : ~0ull;
        kins5(a0, a1, a2, a3, a4, x0);
        kins5(a0, a1, a2, a3, a4, x1);
        #pragma unroll
        for (int off = 32; off >= 1; off >>= 1) {
            u64 b0_ = __shfl_down(a0, off), b1_ = __shfl_down(a1, off),
                b2_ = __shfl_down(a2, off), b3_ = __shfl_down(a3, off),
                b4_ = __shfl_down(a4, off);
            kins5(a0, a1, a2, a3, a4, b0_);
            kins5(a0, a1, a2, a3, a4, b1_);
            kins5(a0, a1, a2, a3, a4, b2_);
            kins5(a0, a1, a2, a3, a4, b3_);
            kins5(a0, a1, a2, a3, a4, b4_);
        }
        if (lane == 0) {
            u64* dst = part + ((size_t)(b0 + s) * NCHUNK + chunk) * K_TOP;
            dst[0] = a0; dst[1] = a1; dst[2] = a2; dst[3] = a3; dst[4] = a4;
        }
    }
}

// Per-source block: merge 80 partial keys -> top-5, then staged magnitude.
__global__ __launch_bounds__(256) void mag_kernel(
    const float* __restrict__ src, const int* __restrict__ ind,
    const float* __restrict__ log_amp, const int* __restrict__ phase_p,
    const float* __restrict__ locs, const float* __restrict__ mag_coef,
    const float* __restrict__ epc_p, const float* __restrict__ depc_p,
    const float* __restrict__ bias, const u64* __restrict__ part,
    float* __restrict__ out)
{
    __shared__ float ctab[N_LOCS];
    __shared__ int   sind[N_LOCS];
    __shared__ int   tsh[K_TOP];

    const int i  = blockIdx.x;
    const int ph = phase_p[0];
    const float denom = fmaxf(mag_coef[ph], 1e-12f);
    const float epc   = epc_p[ph];
    const float depc  = depc_p[ph];

    // wave 0: top-5 of this source's NPART=80 partial keys
    if (threadIdx.x < 64) {
        const int lane = threadIdx.x;
        const u64* p = part + (size_t)i * NPART;
        u64 a0 = ~0ull, a1 = ~0ull, a2 = ~0ull, a3 = ~0ull, a4 = ~0ull;
        kins5(a0, a1, a2, a3, a4, p[lane]);
        if (lane < NPART - 64) kins5(a0, a1, a2, a3, a4, p[lane + 64]);
        #pragma unroll
        for (int off = 32; off >= 1; off >>= 1) {
            u64 b0_ = __shfl_down(a0, off), b1_ = __shfl_down(a1, off),
                b2_ = __shfl_down(a2, off), b3_ = __shfl_down(a3, off),
                b4_ = __shfl_down(a4, off);
            kins5(a0, a1, a2, a3, a4, b0_);
            kins5(a0, a1, a2, a3, a4, b1_);
            kins5(a0, a1, a2, a3, a4, b2_);
            kins5(a0, a1, a2, a3, a4, b3_);
            kins5(a0, a1, a2, a3, a4, b4_);
        }
        if (lane == 0) {
            tsh[0] = (int)(a0 & 0xFFFFFFFFu);
            tsh[1] = (int)(a1 & 0xFFFFFFFFu);
            tsh[2] = (int)(a2 & 0xFFFFFFFFu);
            tsh[3] = (int)(a3 & 0xFFFFFFFFu);
            tsh[4] = (int)(a4 & 0xFFFFFFFFu);
        }
    }
    __syncthreads();

    const int t0 = tsh[0], t1 = tsh[1], t2 = tsh[2], t3 = tsh[3], t4 = tsh[4];

    const float sxv = src[(size_t)i*3 + 0];
    const float syv = src[(size_t)i*3 + 1];
    const float szv = src[(size_t)i*3 + 2];

    // stage: everything that depends only on il (coalesced bias gathers)
    for (int il = threadIdx.x; il < N_LOCS; il += 256) {
        const float lx = locs[(size_t)il*3 + 0];
        const float ly = locs[(size_t)il*3 + 1];
        const float lz = locs[(size_t)il*3 + 2];
        const float dx = sxv - lx, dy = syv - ly;
        const float d0 = sqrtf(fmaf(dy, dy, dx * dx));
        const float pz = log10f(d0 + 1.0f);
        const float pd = log10f(fabsf(szv - lz) + 1.0f);
        const int   col = il * 2 + ph;
        float bsum = bias[(size_t)t0 * (N_LOCS*2) + col]
                   + bias[(size_t)t1 * (N_LOCS*2) + col]
                   + bias[(size_t)t2 * (N_LOCS*2) + col]
                   + bias[(size_t)t3 * (N_LOCS*2) + col]
                   + bias[(size_t)t4 * (N_LOCS*2) + col];
        const float bm = bsum / 5.0f;
        ctab[il] = fmaf(-epc, pz, fmaf(-depc, pd, -bm));
        sind[il] = ind[il];
    }
    __syncthreads();

    for (int l = threadIdx.x; l < N_LOCS; l += 256) {
        const float la = log_amp[(size_t)i * N_LOCS + l];
        out[(size_t)i * N_LOCS + l] = (la + ctab[sind[l]]) / denom;
    }
}

extern "C" void kernel_launch(void* const* d_in, const int* in_sizes, int n_in,
                              void* d_out, int out_size, void* d_ws, size_t ws_size,
                              hipStream_t stream) {
    const float* src      = (const float*)d_in[0];
    const int*   ind      = (const int*)  d_in[1];
    const float* log_amp  = (const float*)d_in[2];
    const int*   phase    = (const int*)  d_in[3];
    const float* locs     = (const float*)d_in[4];
    const float* grid     = (const float*)d_in[5];
    const float* mag_coef = (const float*)d_in[6];
    const float* epc      = (const float*)d_in[7];
    const float* depc     = (const float*)d_in[8];
    const float* bias     = (const float*)d_in[9];
    float* out = (float*)d_out;

    // ws layout
    char* ws = (char*)d_ws;
    float4* g4   = (float4*)ws;                    // 800000 B
    u64*    part = (u64*)(ws + 800000);            // 2048*80*8 = 1310720 B

    prep_kernel<<<(N_GRID + 255) / 256, 256, 0, stream>>>(grid, g4);
    topk_kernel<<<(N_SRC / SPB) * NCHUNK, 256, 0, stream>>>(src, g4, part);
    mag_kernel<<<N_SRC, 256, 0, stream>>>(src, ind, log_amp, phase, locs,
                                          mag_coef, epc, depc, bias, part, out);
}

// Round 5
// 320.092 us; speedup vs baseline: 1.0626x; 1.0626x over previous
//
#include <hip/hip_runtime.h>
#include <math.h>

#define N_SRC  2048
#define N_GRID 50000
#define N_LOCS 500
#define K_TOP  5
#define SPB    8                    // sources per block (topk)
#define NCHUNK 16                   // grid chunks
#define CHUNK  (N_GRID / NCHUNK)    // 3125
#define CAP    128                  // LDS candidate list capacity per source
#define NPART  (NCHUNK * K_TOP)     // 80 partial keys per source

typedef unsigned long long u64;

// Monotone pack: order-preserving f32 bits <<32 | grid index.
// Smallest key == smallest d2; ties -> smallest index (matches jax.lax.top_k).
__device__ __forceinline__ u64 pack_key(float d2, int j) {
    unsigned int b = __float_as_uint(d2);
    unsigned int m = (unsigned int)(-(int)(b >> 31)) | 0x80000000u;
    b ^= m;
    return ((u64)b << 32) | (u64)(unsigned int)j;
}

// Identical fmaf sequence in both passes -> bit-identical d2 (and identical
// to rounds 1-3, so the selected index set is unchanged).
__device__ __forceinline__ float dist2(float sx, float sy, float sz, float s2,
                                       float4 g) {
    float dot = fmaf(sz, g.z, fmaf(sy, g.y, sx * g.x));
    return fmaf(-2.0f, dot, s2 + g.w);
}

// grid -> (x,y,z)/1000 + precomputed g2, as float4 (division amortized once)
__global__ __launch_bounds__(256) void prep_kernel(
    const float* __restrict__ grid, float4* __restrict__ g4)
{
    int j = blockIdx.x * 256 + threadIdx.x;
    if (j < N_GRID) {
        float gx = grid[(size_t)j*3 + 0] / 1000.0f;
        float gy = grid[(size_t)j*3 + 1] / 1000.0f;
        float gz = grid[(size_t)j*3 + 2] / 1000.0f;
        float g2 = fmaf(gz, gz, fmaf(gy, gy, gx * gx));
        g4[j] = make_float4(gx, gy, gz, g2);
    }
}

__global__ __launch_bounds__(256) void topk_kernel(
    const float* __restrict__ src, const float4* __restrict__ g4,
    u64* __restrict__ part)
{
    __shared__ float minsL[SPB][256];
    __shared__ float TL[SPB];
    __shared__ int   cntL[SPB];
    __shared__ u64   listL[SPB][CAP];

    const int tid   = threadIdx.x;
    const int grp   = blockIdx.x & 255;        // source octet (N_SRC/SPB = 256)
    const int chunk = blockIdx.x >> 8;         // grid chunk
    const int b0    = grp * SPB;
    const int j0    = chunk * CHUNK;
    const int j1    = j0 + CHUNK;

    float sx[SPB], sy[SPB], sz[SPB], s2[SPB];
    #pragma unroll
    for (int s = 0; s < SPB; ++s) {
        const float* p = src + (size_t)(b0 + s) * 3;
        float x = p[0] / 1000.0f, y = p[1] / 1000.0f, z = p[2] / 1000.0f;
        sx[s] = x; sy[s] = y; sz[s] = z;
        s2[s] = fmaf(z, z, fmaf(y, y, x * x));
    }

    // ---- pass A: per-thread min distance per source ----
    float mn[SPB];
    #pragma unroll
    for (int s = 0; s < SPB; ++s) mn[s] = INFINITY;

    for (int j = j0 + tid; j < j1; j += 256) {
        float4 g = g4[j];
        #pragma unroll
        for (int s = 0; s < SPB; ++s)
            mn[s] = fminf(mn[s], dist2(sx[s], sy[s], sz[s], s2[s], g));
    }
    #pragma unroll
    for (int s = 0; s < SPB; ++s) minsL[s][tid] = mn[s];
    if (tid < SPB) cntL[tid] = 0;
    __syncthreads();

    // ---- threshold T[s]: exact 5th-smallest of the 64 lane-minima ----
    // (the 5 smallest lane-minima are 5 distinct grid candidates <= T,
    //  so the true top-5 all satisfy d2 <= T). Rank-selection, no sort.
    const int lane = tid & 63;
    const int w    = tid >> 6;
    #pragma unroll
    for (int ss = 0; ss < 2; ++ss) {
        const int s = w + ss * 4;                    // wave w owns sources w, w+4
        float v = fminf(fminf(minsL[s][lane*4 + 0], minsL[s][lane*4 + 1]),
                        fminf(minsL[s][lane*4 + 2], minsL[s][lane*4 + 3]));
        minsL[s][lane] = v;          // lane-minima (single wave owns row s: safe)
        int rank = 0;
        for (int r = 0; r < 64; ++r)                 // LDS broadcast reads
            rank += (minsL[s][r] < v) ? 1 : 0;
        float t = (rank < K_TOP) ? v : -INFINITY;    // max of ranks<5 == 5th val
        #pragma unroll
        for (int off = 32; off >= 1; off >>= 1)
            t = fmaxf(t, __shfl_xor(t, off));
        if (lane == 0) TL[s] = t;
    }
    __syncthreads();

    float Ts[SPB];
    #pragma unroll
    for (int s = 0; s < SPB; ++s) Ts[s] = TL[s];

    // ---- pass B: collect candidates with d2 <= T (expected ~5-10) ----
    for (int j = j0 + tid; j < j1; j += 256) {
        float4 g = g4[j];
        #pragma unroll
        for (int s = 0; s < SPB; ++s) {
            float d2 = dist2(sx[s], sy[s], sz[s], s2[s], g);
            if (d2 <= Ts[s]) {
                int p = atomicAdd(&cntL[s], 1);
                if (p < CAP) listL[s][p] = pack_key(d2, j);
            }
        }
    }
    __syncthreads();

    // ---- exact top-5 of collected list via rank selection ----
    // keys are unique (distinct j) -> unique ranks -> direct scatter.
    #pragma unroll
    for (int ss = 0; ss < 2; ++ss) {
        const int s = w + ss * 4;
        int n = cntL[s]; n = n < CAP ? n : CAP;      // n >= 5 guaranteed
        u64 k0 = (lane      < n) ? listL[s][lane]      : ~0ull;
        u64 k1 = (lane + 64 < n) ? listL[s][lane + 64] : ~0ull;
        int r0 = 0, r1 = 0;
        for (int r = 0; r < n; ++r) {                // LDS broadcast reads
            u64 kr = listL[s][r];
            r0 += (kr < k0) ? 1 : 0;
            r1 += (kr < k1) ? 1 : 0;
        }
        u64* dst = part + ((size_t)(b0 + s) * NCHUNK + chunk) * K_TOP;
        if (lane      < n && r0 < K_TOP) dst[r0] = k0;
        if (lane + 64 < n && r1 < K_TOP) dst[r1] = k1;
    }
}

// Per-source block: rank-merge 80 partial keys -> top-5, then staged magnitude.
__global__ __launch_bounds__(256) void mag_kernel(
    const float* __restrict__ src, const int* __restrict__ ind,
    const float* __restrict__ log_amp, const int* __restrict__ phase_p,
    const float* __restrict__ locs, const float* __restrict__ mag_coef,
    const float* __restrict__ epc_p, const float* __restrict__ depc_p,
    const float* __restrict__ bias, const u64* __restrict__ part,
    float* __restrict__ out)
{
    __shared__ float ctab[N_LOCS];
    __shared__ int   sind[N_LOCS];
    __shared__ u64   keysL[NPART];
    __shared__ int   tsh[K_TOP];

    const int tid = threadIdx.x;
    const int i   = blockIdx.x;
    const int ph  = phase_p[0];
    const float denom = fmaxf(mag_coef[ph], 1e-12f);
    const float epc   = epc_p[ph];
    const float depc  = depc_p[ph];

    if (tid < NPART) keysL[tid] = part[(size_t)i * NPART + tid];
    __syncthreads();
    if (tid < NPART) {
        u64 k = keysL[tid];
        int rk = 0;
        for (int r = 0; r < NPART; ++r)
            rk += (keysL[r] < k) ? 1 : 0;            // unique keys -> unique rank
        if (rk < K_TOP) tsh[rk] = (int)(k & 0xFFFFFFFFu);
    }
    __syncthreads();

    const int t0 = tsh[0], t1 = tsh[1], t2 = tsh[2], t3 = tsh[3], t4 = tsh[4];

    const float sxv = src[(size_t)i*3 + 0];
    const float syv = src[(size_t)i*3 + 1];
    const float szv = src[(size_t)i*3 + 2];

    // stage: everything that depends only on il (coalesced bias gathers)
    for (int il = tid; il < N_LOCS; il += 256) {
        const float lx = locs[(size_t)il*3 + 0];
        const float ly = locs[(size_t)il*3 + 1];
        const float lz = locs[(size_t)il*3 + 2];
        const float dx = sxv - lx, dy = syv - ly;
        const float d0 = sqrtf(fmaf(dy, dy, dx * dx));
        const float pz = log10f(d0 + 1.0f);
        const float pd = log10f(fabsf(szv - lz) + 1.0f);
        const int   col = il * 2 + ph;
        float bsum = bias[(size_t)t0 * (N_LOCS*2) + col]
                   + bias[(size_t)t1 * (N_LOCS*2) + col]
                   + bias[(size_t)t2 * (N_LOCS*2) + col]
                   + bias[(size_t)t3 * (N_LOCS*2) + col]
                   + bias[(size_t)t4 * (N_LOCS*2) + col];
        const float bm = bsum / 5.0f;
        ctab[il] = fmaf(-epc, pz, fmaf(-depc, pd, -bm));
        sind[il] = ind[il];
    }
    __syncthreads();

    for (int l = tid; l < N_LOCS; l += 256) {
        const float la = log_amp[(size_t)i * N_LOCS + l];
        out[(size_t)i * N_LOCS + l] = (la + ctab[sind[l]]) / denom;
    }
}

extern "C" void kernel_launch(void* const* d_in, const int* in_sizes, int n_in,
                              void* d_out, int out_size, void* d_ws, size_t ws_size,
                              hipStream_t stream) {
    const float* src      = (const float*)d_in[0];
    const int*   ind      = (const int*)  d_in[1];
    const float* log_amp  = (const float*)d_in[2];
    const int*   phase    = (const int*)  d_in[3];
    const float* locs     = (const float*)d_in[4];
    const float* grid     = (const float*)d_in[5];
    const float* mag_coef = (const float*)d_in[6];
    const float* epc      = (const float*)d_in[7];
    const float* depc     = (const float*)d_in[8];
    const float* bias     = (const float*)d_in[9];
    float* out = (float*)d_out;

    // ws layout
    char* ws = (char*)d_ws;
    float4* g4   = (float4*)ws;                    // 800000 B
    u64*    part = (u64*)(ws + 800000);            // 2048*80*8 = 1310720 B

    prep_kernel<<<(N_GRID + 255) / 256, 256, 0, stream>>>(grid, g4);
    topk_kernel<<<(N_SRC / SPB) * NCHUNK, 256, 0, stream>>>(src, g4, part);
    mag_kernel<<<N_SRC, 256, 0, stream>>>(src, ind, log_amp, phase, locs,
                                          mag_coef, epc, depc, bias, part, out);
}